// Round 12
// baseline (75.737 us; speedup 1.0000x reference)
//
#include <hip/hip_runtime.h>
#include <hip/hip_bf16.h>

// Problem constants
constexpr int Bn = 4096;   // batch
constexpr int Vn = 64;     // nodes
constexpr int Hn = 512;    // hidden

typedef __attribute__((ext_vector_type(8))) short bf16x8;
typedef __attribute__((ext_vector_type(4))) float f32x4;
typedef __attribute__((ext_vector_type(8))) unsigned short u16x8;
typedef __attribute__((ext_vector_type(4))) _Float16 f16x4;
typedef __attribute__((ext_vector_type(2))) __fp16 fp16v2;

union h4cast { fp16v2 h2[2]; f16x4 f4; };

__device__ __forceinline__ unsigned short f2bf(float f) {
    union { float f; unsigned int u; } x; x.f = f;
    unsigned int u = x.u;
    u += 0x7fffu + ((u >> 16) & 1u);   // round-to-nearest-even
    return (unsigned short)(u >> 16);
}

// ---------------------------------------------------------------------------
// Prep (1152 blocks x 256) — massive TLP hides the scattered W1/x reads:
//  blocks 0..1023: bfrag[v] = sigmoid(adj)*W1 in mfma frag layout
//    flat = (((v*32+nt)*2+ks)*64+lane)*8+e, n = nt*16+(lane&15),
//    k = ks*32+(lane>>4)*8+e.  XCD-swizzled: panel v produced on XCD v>>3.
//  blocks 1024..1151: afrag = x fp32->bf16, flat = ((mt*2+ks)*64+lane)*8+e,
//    b = mt*16+(lane&15), k = ks*32+(lane>>4)*8+e.
// ---------------------------------------------------------------------------
__global__ void prep_all(const float* __restrict__ adjw,
                         const float* __restrict__ W1,
                         const float* __restrict__ x,
                         unsigned short* __restrict__ bfrag,
                         unsigned short* __restrict__ afrag) {
    if (blockIdx.x < 1024) {
        int nb   = (blockIdx.x & 7) * 128 + (blockIdx.x >> 3);
        int tid  = nb * 256 + threadIdx.x;
        int lane = tid & 63;
        int ks   = (tid >> 6) & 1;
        int nt   = (tid >> 7) & 31;
        int v    = tid >> 12;

        int n     = nt * 16 + (lane & 15);
        int kbase = ks * 32 + ((lane >> 4) << 3);

        u16x8 o;
#pragma unroll
        for (int e = 0; e < 8; ++e) {
            int k = kbase + e;
            float val = 0.f;
            if (k != v) {
                float aw = adjw[v * Vn + k];
                float s  = 1.f / (1.f + __expf(-aw));
                int  j   = k - (k > v);
                val = s * W1[((size_t)(v * (Vn - 1) + j)) * Hn + n];
            }
            o[e] = f2bf(val);
        }
        *reinterpret_cast<u16x8*>(bfrag + (size_t)tid * 8) = o;
    } else {
        int tid  = (blockIdx.x - 1024) * 256 + threadIdx.x;   // 0..32767
        int lane = tid & 63;
        int ks   = (tid >> 6) & 1;
        int mt   = tid >> 7;

        int b     = mt * 16 + (lane & 15);
        int kbase = ks * 32 + ((lane >> 4) << 3);

        u16x8 o;
#pragma unroll
        for (int e = 0; e < 8; ++e)
            o[e] = f2bf(x[(size_t)b * Vn + kbase + e]);
        *reinterpret_cast<u16x8*>(afrag + (size_t)tid * 8) = o;
    }
}

// ---------------------------------------------------------------------------
// Main: 1024 blocks = (v, ro) with ro in 0..15 (256 rows). 512 thr / 8 waves;
// wave w owns h-cols [w*64, w*64+64). ONE-SHOT staging: the whole 32KB
// x-slice is loaded (4 loads/thread) and LDS-written up front, ONE barrier,
// then 16 m-tiles run with zero barriers (ds_read offsets are compile-time
// immediates). Per mt: 8x mfma16x16x32_bf16 (b1 C-init), relu via packed
// cvt_pkrtz, 4x mfma16x16x16f16 W2-dot in two acc chains. Partials in LDS
// stride-9; barrier; final pass writes out. 41KB LDS -> 3 blocks/CU.
// ---------------------------------------------------------------------------
__global__ __launch_bounds__(512, 6)
void main_k(const unsigned short* __restrict__ afrag,
            const unsigned short* __restrict__ bfrag,
            const float* __restrict__ b1, const float* __restrict__ W2,
            const float* __restrict__ b2, float* __restrict__ out) {
    __shared__ __align__(16) unsigned char smem[32768 + 256 * 9 * 4];
    float* partials = reinterpret_cast<float*>(smem + 32768);

    int t    = threadIdx.x;
    int wid  = t >> 6;
    int lane = t & 63;
    // XCD-affine: all 16 ro-blocks of v live on XCD v>>3 (matches prep)
    int v    = (blockIdx.x & 7) * 8 + ((blockIdx.x >> 3) & 7);
    int ro   = blockIdx.x >> 6;            // 0..15, 256 rows each

    // ---- issue ALL staging loads up front (4x 16B/thread, coalesced) ----
    const u16x8* asrc = reinterpret_cast<const u16x8*>(afrag) + (size_t)ro * 2048;
    u16x8 s0 = asrc[t];
    u16x8 s1 = asrc[512 + t];
    u16x8 s2 = asrc[1024 + t];
    u16x8 s3 = asrc[1536 + t];

    // ---- persistent per-wave operands (coalesced from pre-digested data) ----
    const unsigned short* wpan = bfrag + (size_t)v * 32768;
    bf16x8 Wf[4][2];
#pragma unroll
    for (int j = 0; j < 4; ++j)
#pragma unroll
        for (int ks = 0; ks < 2; ++ks)
            Wf[j][ks] = *reinterpret_cast<const bf16x8*>(
                wpan + ((size_t)((wid * 4 + j) * 2 + ks)) * 512 + lane * 8);

    int hi4 = (lane >> 4) << 2;
    f32x4 b1bc[4];
    f16x4 w2A[4];
#pragma unroll
    for (int j = 0; j < 4; ++j) {
        int ntg = wid * 4 + j;
        b1bc[j] = *reinterpret_cast<const f32x4*>(b1 + v * Hn + ntg * 16 + hi4);
        f32x4 wv = *reinterpret_cast<const f32x4*>(W2 + v * Hn + ntg * 16 + hi4);
#pragma unroll
        for (int e = 0; e < 4; ++e) w2A[j][e] = (_Float16)wv[e];
    }

    // ---- write staged data, single barrier ----
    *reinterpret_cast<u16x8*>(smem + (size_t)t * 16)            = s0;
    *reinterpret_cast<u16x8*>(smem + (size_t)(512 + t) * 16)    = s1;
    *reinterpret_cast<u16x8*>(smem + (size_t)(1024 + t) * 16)   = s2;
    *reinterpret_cast<u16x8*>(smem + (size_t)(1536 + t) * 16)   = s3;
    __syncthreads();

    // ---- barrier-free compute: 16 m-tiles ----
#pragma unroll
    for (int mt = 0; mt < 16; ++mt) {
        bf16x8 a0 = *reinterpret_cast<const bf16x8*>(smem + ((mt * 2 + 0) * 64 + lane) * 16);
        bf16x8 a1 = *reinterpret_cast<const bf16x8*>(smem + ((mt * 2 + 1) * 64 + lane) * 16);
        f32x4 accA = {0.f, 0.f, 0.f, 0.f};
        f32x4 accB = {0.f, 0.f, 0.f, 0.f};
#pragma unroll
        for (int p = 0; p < 2; ++p) {
#pragma unroll
            for (int q = 0; q < 2; ++q) {
                int j = 2 * p + q;
                f32x4 c1 = __builtin_amdgcn_mfma_f32_16x16x32_bf16(Wf[j][0], a0, b1bc[j], 0, 0, 0);
                c1 = __builtin_amdgcn_mfma_f32_16x16x32_bf16(Wf[j][1], a1, c1, 0, 0, 0);
                h4cast hc;
                hc.h2[0] = __builtin_amdgcn_cvt_pkrtz(fmaxf(c1[0], 0.f), fmaxf(c1[1], 0.f));
                hc.h2[1] = __builtin_amdgcn_cvt_pkrtz(fmaxf(c1[2], 0.f), fmaxf(c1[3], 0.f));
                if (q == 0)
                    accA = __builtin_amdgcn_mfma_f32_16x16x16f16(w2A[j], hc.f4, accA, 0, 0, 0);
                else
                    accB = __builtin_amdgcn_mfma_f32_16x16x16f16(w2A[j], hc.f4, accB, 0, 0, 0);
            }
        }
        // D rows all equal (A broadcast); lanes 0..15 reg 0 = row 0
        if (lane < 16)
            partials[(mt * 16 + lane) * 9 + wid] = accA[0] + accB[0];
    }
    __syncthreads();

    // ---- final cross-wave reduce: thread t (<256) owns row ro*256+t ----
    if (t < 256) {
        float s = b2[v];
#pragma unroll
        for (int w = 0; w < 8; ++w) s += partials[t * 9 + w];
        out[(size_t)(ro * 256 + t) * Vn + v] = s;
    }
}

extern "C" void kernel_launch(void* const* d_in, const int* in_sizes, int n_in,
                              void* d_out, int out_size, void* d_ws, size_t ws_size,
                              hipStream_t stream) {
    const float* x    = (const float*)d_in[0];
    const float* adjw = (const float*)d_in[1];
    const float* W1   = (const float*)d_in[2];
    const float* b1   = (const float*)d_in[3];
    const float* W2   = (const float*)d_in[4];
    const float* b2   = (const float*)d_in[5];
    float* out = (float*)d_out;

    // workspace: bfrag = 64*64*512 u16 (4 MiB), afrag = 4096*64 u16 (512 KiB)
    unsigned short* bfrag = (unsigned short*)d_ws;
    unsigned short* afrag = bfrag + (size_t)Vn * Vn * Hn;

    prep_all<<<1152, 256, 0, stream>>>(adjw, W1, x, bfrag, afrag);
    main_k<<<1024, 512, 0, stream>>>(afrag, bfrag, b1, W2, b2, out);
}

// Round 13
// 30.418 us; speedup vs baseline: 2.4898x; 2.4898x over previous
//
#include <hip/hip_runtime.h>
#include <hip/hip_bf16.h>

// Problem constants
constexpr int Bn = 4096;   // batch
constexpr int Vn = 64;     // nodes
constexpr int Hn = 512;    // hidden

typedef __attribute__((ext_vector_type(8))) short bf16x8;
typedef __attribute__((ext_vector_type(4))) float f32x4;
typedef __attribute__((ext_vector_type(8))) unsigned short u16x8;
typedef __attribute__((ext_vector_type(4))) _Float16 f16x4;
typedef __attribute__((ext_vector_type(2))) __fp16 fp16v2;

union h4cast { fp16v2 h2[2]; f16x4 f4; };

__device__ __forceinline__ unsigned short f2bf(float f) {
    union { float f; unsigned int u; } x; x.f = f;
    unsigned int u = x.u;
    u += 0x7fffu + ((u >> 16) & 1u);   // round-to-nearest-even
    return (unsigned short)(u >> 16);
}

// ---------------------------------------------------------------------------
// Prep (1152 blocks x 256) — massive TLP hides the scattered W1/x reads:
//  blocks 0..1023: bfrag[v] = sigmoid(adj)*W1 in mfma frag layout
//    flat = (((v*32+nt)*2+ks)*64+lane)*8+e, n = nt*16+(lane&15),
//    k = ks*32+(lane>>4)*8+e.  XCD-swizzled: panel v produced on XCD v>>3.
//  blocks 1024..1151: afrag = x fp32->bf16, flat = ((mt*2+ks)*64+lane)*8+e,
//    b = mt*16+(lane&15), k = ks*32+(lane>>4)*8+e.
// ---------------------------------------------------------------------------
__global__ void prep_all(const float* __restrict__ adjw,
                         const float* __restrict__ W1,
                         const float* __restrict__ x,
                         unsigned short* __restrict__ bfrag,
                         unsigned short* __restrict__ afrag) {
    if (blockIdx.x < 1024) {
        int nb   = (blockIdx.x & 7) * 128 + (blockIdx.x >> 3);
        int tid  = nb * 256 + threadIdx.x;
        int lane = tid & 63;
        int ks   = (tid >> 6) & 1;
        int nt   = (tid >> 7) & 31;
        int v    = tid >> 12;

        int n     = nt * 16 + (lane & 15);
        int kbase = ks * 32 + ((lane >> 4) << 3);

        u16x8 o;
#pragma unroll
        for (int e = 0; e < 8; ++e) {
            int k = kbase + e;
            float val = 0.f;
            if (k != v) {
                float aw = adjw[v * Vn + k];
                float s  = 1.f / (1.f + __expf(-aw));
                int  j   = k - (k > v);
                val = s * W1[((size_t)(v * (Vn - 1) + j)) * Hn + n];
            }
            o[e] = f2bf(val);
        }
        *reinterpret_cast<u16x8*>(bfrag + (size_t)tid * 8) = o;
    } else {
        int tid  = (blockIdx.x - 1024) * 256 + threadIdx.x;   // 0..32767
        int lane = tid & 63;
        int ks   = (tid >> 6) & 1;
        int mt   = tid >> 7;

        int b     = mt * 16 + (lane & 15);
        int kbase = ks * 32 + ((lane >> 4) << 3);

        u16x8 o;
#pragma unroll
        for (int e = 0; e < 8; ++e)
            o[e] = f2bf(x[(size_t)b * Vn + kbase + e]);
        *reinterpret_cast<u16x8*>(afrag + (size_t)tid * 8) = o;
    }
}

// ---------------------------------------------------------------------------
// Main: 1024 blocks = (v, ro) with ro in 0..15 (256 rows). 512 thr / 8 waves;
// wave w owns h-cols [w*64, w*64+64). ONE-SHOT staging: the whole 32KB
// x-slice is loaded (4 loads/thread) and LDS-written up front, ONE barrier,
// then 16 m-tiles run with zero barriers (ds_read offsets are compile-time
// immediates). Per mt: 8x mfma16x16x32_bf16 (b1 C-init), relu via packed
// cvt_pkrtz, 4x mfma16x16x16f16 W2-dot in two acc chains. Partials in LDS
// stride-9; barrier; final pass writes out. 41KB LDS -> 3 blocks/CU.
// launch_bounds (512,4): VGPR cap 128 — R12's (512,6) forced VGPR=40 and
// spilled to scratch (FETCH 17->49 MB). Never over-constrain the allocator.
// ---------------------------------------------------------------------------
__global__ __launch_bounds__(512, 4)
void main_k(const unsigned short* __restrict__ afrag,
            const unsigned short* __restrict__ bfrag,
            const float* __restrict__ b1, const float* __restrict__ W2,
            const float* __restrict__ b2, float* __restrict__ out) {
    __shared__ __align__(16) unsigned char smem[32768 + 256 * 9 * 4];
    float* partials = reinterpret_cast<float*>(smem + 32768);

    int t    = threadIdx.x;
    int wid  = t >> 6;
    int lane = t & 63;
    // XCD-affine: all 16 ro-blocks of v live on XCD v>>3 (matches prep)
    int v    = (blockIdx.x & 7) * 8 + ((blockIdx.x >> 3) & 7);
    int ro   = blockIdx.x >> 6;            // 0..15, 256 rows each

    // ---- issue ALL staging loads up front (4x 16B/thread, coalesced) ----
    const u16x8* asrc = reinterpret_cast<const u16x8*>(afrag) + (size_t)ro * 2048;
    u16x8 s0 = asrc[t];
    u16x8 s1 = asrc[512 + t];
    u16x8 s2 = asrc[1024 + t];
    u16x8 s3 = asrc[1536 + t];

    // ---- persistent per-wave operands (coalesced from pre-digested data) ----
    const unsigned short* wpan = bfrag + (size_t)v * 32768;
    bf16x8 Wf[4][2];
#pragma unroll
    for (int j = 0; j < 4; ++j)
#pragma unroll
        for (int ks = 0; ks < 2; ++ks)
            Wf[j][ks] = *reinterpret_cast<const bf16x8*>(
                wpan + ((size_t)((wid * 4 + j) * 2 + ks)) * 512 + lane * 8);

    int hi4 = (lane >> 4) << 2;
    f32x4 b1bc[4];
    f16x4 w2A[4];
#pragma unroll
    for (int j = 0; j < 4; ++j) {
        int ntg = wid * 4 + j;
        b1bc[j] = *reinterpret_cast<const f32x4*>(b1 + v * Hn + ntg * 16 + hi4);
        f32x4 wv = *reinterpret_cast<const f32x4*>(W2 + v * Hn + ntg * 16 + hi4);
#pragma unroll
        for (int e = 0; e < 4; ++e) w2A[j][e] = (_Float16)wv[e];
    }

    // ---- write staged data, single barrier ----
    *reinterpret_cast<u16x8*>(smem + (size_t)t * 16)            = s0;
    *reinterpret_cast<u16x8*>(smem + (size_t)(512 + t) * 16)    = s1;
    *reinterpret_cast<u16x8*>(smem + (size_t)(1024 + t) * 16)   = s2;
    *reinterpret_cast<u16x8*>(smem + (size_t)(1536 + t) * 16)   = s3;
    __syncthreads();

    // ---- barrier-free compute: 16 m-tiles ----
#pragma unroll
    for (int mt = 0; mt < 16; ++mt) {
        bf16x8 a0 = *reinterpret_cast<const bf16x8*>(smem + ((mt * 2 + 0) * 64 + lane) * 16);
        bf16x8 a1 = *reinterpret_cast<const bf16x8*>(smem + ((mt * 2 + 1) * 64 + lane) * 16);
        f32x4 accA = {0.f, 0.f, 0.f, 0.f};
        f32x4 accB = {0.f, 0.f, 0.f, 0.f};
#pragma unroll
        for (int p = 0; p < 2; ++p) {
#pragma unroll
            for (int q = 0; q < 2; ++q) {
                int j = 2 * p + q;
                f32x4 c1 = __builtin_amdgcn_mfma_f32_16x16x32_bf16(Wf[j][0], a0, b1bc[j], 0, 0, 0);
                c1 = __builtin_amdgcn_mfma_f32_16x16x32_bf16(Wf[j][1], a1, c1, 0, 0, 0);
                h4cast hc;
                hc.h2[0] = __builtin_amdgcn_cvt_pkrtz(fmaxf(c1[0], 0.f), fmaxf(c1[1], 0.f));
                hc.h2[1] = __builtin_amdgcn_cvt_pkrtz(fmaxf(c1[2], 0.f), fmaxf(c1[3], 0.f));
                if (q == 0)
                    accA = __builtin_amdgcn_mfma_f32_16x16x16f16(w2A[j], hc.f4, accA, 0, 0, 0);
                else
                    accB = __builtin_amdgcn_mfma_f32_16x16x16f16(w2A[j], hc.f4, accB, 0, 0, 0);
            }
        }
        // D rows all equal (A broadcast); lanes 0..15 reg 0 = row 0
        if (lane < 16)
            partials[(mt * 16 + lane) * 9 + wid] = accA[0] + accB[0];
    }
    __syncthreads();

    // ---- final cross-wave reduce: thread t (<256) owns row ro*256+t ----
    if (t < 256) {
        float s = b2[v];
#pragma unroll
        for (int w = 0; w < 8; ++w) s += partials[t * 9 + w];
        out[(size_t)(ro * 256 + t) * Vn + v] = s;
    }
}

extern "C" void kernel_launch(void* const* d_in, const int* in_sizes, int n_in,
                              void* d_out, int out_size, void* d_ws, size_t ws_size,
                              hipStream_t stream) {
    const float* x    = (const float*)d_in[0];
    const float* adjw = (const float*)d_in[1];
    const float* W1   = (const float*)d_in[2];
    const float* b1   = (const float*)d_in[3];
    const float* W2   = (const float*)d_in[4];
    const float* b2   = (const float*)d_in[5];
    float* out = (float*)d_out;

    // workspace: bfrag = 64*64*512 u16 (4 MiB), afrag = 4096*64 u16 (512 KiB)
    unsigned short* bfrag = (unsigned short*)d_ws;
    unsigned short* afrag = bfrag + (size_t)Vn * Vn * Hn;

    prep_all<<<1152, 256, 0, stream>>>(adjw, W1, x, bfrag, afrag);
    main_k<<<1024, 512, 0, stream>>>(afrag, bfrag, b1, W2, b2, out);
}